// Round 16
// baseline (895.965 us; speedup 1.0000x reference)
//
#include <hip/hip_runtime.h>
#include <hip/hip_bf16.h>

#define BB 16
#define TT 1024
#define CC 2048
#define TS 32   // wkv scan segment length

typedef __attribute__((ext_vector_type(4))) float f32x4;
typedef __attribute__((ext_vector_type(8))) short bf16x8;

__device__ __forceinline__ unsigned short f2bf(float f) {
  union { float f; unsigned u; } x; x.f = f;
  unsigned r = x.u + 0x7fffu + ((x.u >> 16) & 1u);
  return (unsigned short)(r >> 16);
}
__device__ __forceinline__ float bf2f(unsigned short u) {
  union { unsigned u; float f; } x; x.u = ((unsigned)u) << 16;
  return x.f;
}

__device__ __forceinline__ ushort4 mix4(float4 a, float4 b, float4 m) {
  ushort4 o;
  o.x = f2bf(a.x * m.x + b.x * (1.f - m.x));
  o.y = f2bf(a.y * m.y + b.y * (1.f - m.y));
  o.z = f2bf(a.z * m.z + b.z * (1.f - m.z));
  o.w = f2bf(a.w * m.w + b.w * (1.f - m.w));
  return o;
}

__global__ void f2bf_all(const float* __restrict__ w0, const float* __restrict__ w1,
                         const float* __restrict__ w2, const float* __restrict__ w3,
                         unsigned short* __restrict__ o0, unsigned short* __restrict__ o1,
                         unsigned short* __restrict__ o2, unsigned short* __restrict__ o3,
                         int n4each) {
  const float* ws[4] = {w0, w1, w2, w3};
  unsigned short* os[4] = {o0, o1, o2, o3};
  int total = 4 * n4each;
  for (int i = blockIdx.x * blockDim.x + threadIdx.x; i < total;
       i += gridDim.x * blockDim.x) {
    int seg = i / n4each, j = i - seg * n4each;
    float4 v = ((const float4*)ws[seg])[j];
    ushort4 o;
    o.x = f2bf(v.x); o.y = f2bf(v.y); o.z = f2bf(v.z); o.w = f2bf(v.w);
    ((ushort4*)os[seg])[j] = o;
  }
}

// time-shift mix, ROW-PAIRED (R15): each thread produces t=2j and 2j+1.
__global__ void mix_kernel(const float* __restrict__ x,
                           const float* __restrict__ tmk,
                           const float* __restrict__ tmv,
                           const float* __restrict__ tmr,
                           unsigned short* __restrict__ xk,
                           unsigned short* __restrict__ xv,
                           unsigned short* __restrict__ xr,
                           int t0, int Tc) {
  const int C4 = CC / 4;
  const int halfT = Tc >> 1;
  const int total = BB * halfT * C4;
  for (int g = blockIdx.x * blockDim.x + threadIdx.x; g < total;
       g += gridDim.x * blockDim.x) {
    int cg = g % C4;
    int rp = g / C4;
    int j = rp % halfT;
    int b = rp / halfT;
    int tl = 2 * j;
    int t = t0 + tl;
    size_t gidx0 = (size_t)(b * TT + t) * C4 + cg;
    float4 x0 = ((const float4*)x)[gidx0];
    float4 x1 = ((const float4*)x)[gidx0 + C4];
    float4 xm = make_float4(0.f, 0.f, 0.f, 0.f);
    if (t > 0) xm = ((const float4*)x)[gidx0 - C4];
    float4 mk = ((const float4*)tmk)[cg];
    float4 mv = ((const float4*)tmv)[cg];
    float4 mr = ((const float4*)tmr)[cg];
    size_t o0 = (size_t)(b * Tc + tl) * C4 + cg;
    ((ushort4*)xk)[o0] = mix4(x0, xm, mk);
    ((ushort4*)xv)[o0] = mix4(x0, xm, mv);
    ((ushort4*)xr)[o0] = mix4(x0, xm, mr);
    ((ushort4*)xk)[o0 + C4] = mix4(x1, x0, mk);
    ((ushort4*)xv)[o0 + C4] = mix4(x1, x0, mv);
    ((ushort4*)xr)[o0 + C4] = mix4(x1, x0, mr);
  }
}

// ---------------------------------------------------------------------------
// 256x256 GEMM, BK=32, 8 waves (2x4), DOUBLE-buffered 64KB LDS -> TWO BLOCKS
// PER CU. R14 retried with the launch-bounds bug fixed: (512,2) lets the
// allocator use 128 VGPRs (R13/R15 body compiled to exactly 128), and at
// 128 VGPR x 16 waves = full file + 2x64KB LDS, the HW co-schedules 2
// blocks/CU with INDEPENDENT barriers -> one block's ds_read/drain phase
// overlaps the other's MFMA phase (m114). R14's (512,4) forced a 64-VGPR
// budget and spilled acc (4.2GB scratch) — that was the regression, not the
// structure. Body(t): RDT(t); STAGE(t+1); vmcnt(0); BAR; MFMA(t).
// XCD-bijective block swizzle. C[orow,N] = A[M,K]*B[N,K]^T.
// ---------------------------------------------------------------------------
template<bool BF16OUT>
__global__ __launch_bounds__(512, 2)
void gemm256(const unsigned short* __restrict__ A,
             const unsigned short* __restrict__ B,
             void* __restrict__ Cv, int N, int K, int tcShift, int t0) {
  __shared__ __align__(1024) unsigned char lds[65536];
  const int tid = threadIdx.x;
  const int lane = tid & 63;
  const int wid = tid >> 6;
  const int wr = wid >> 2;   // 0..1
  const int wc = wid & 3;    // 0..3

  const int nwg = gridDim.x;
  const int cpx = nwg >> 3;
  const int bid = blockIdx.x;
  const int wg = (bid & 7) * cpx + (bid >> 3);
  const int bcolN = N >> 8;
  const int brow = wg / bcolN;
  const int bcol = wg % bcolN;

  // staging map: thread -> (row = tid>>2, 16B chunk (tid&3), swizzled source col)
  const int strow = tid >> 2;                                   // 0..127
  const int scelem = (((tid & 3) ^ ((tid >> 3) & 3)) << 3);     // elems
  const unsigned short* sA0 = A + (size_t)(brow * 256 + strow) * K + scelem;
  const unsigned short* sA1 = A + (size_t)(brow * 256 + 128 + strow) * K + scelem;
  const unsigned short* sB0 = B + (size_t)(bcol * 256 + strow) * K + scelem;
  const unsigned short* sB1 = B + (size_t)(bcol * 256 + 128 + strow) * K + scelem;

  // read map (identical to R10/R13: measured 0 bank conflicts)
  const int frow = lane & 15;
  const int fhi = (lane >> 4) << 4;                  // k-group byte
  const int fsw = ((frow >> 1) & 3) << 4;            // swizzle (lane-const)
  const int aOff = (wr * 128 + frow) * 64 + (fhi ^ fsw);           // + buf*16384
  const int bOff = 32768 + (wc * 64 + frow) * 64 + (fhi ^ fsw);    // + buf*16384
  const int ldsW = wid * 1024;

#define STG(ptr, ldsOff, eoff)                                                 \
  __builtin_amdgcn_global_load_lds(                                            \
      (const __attribute__((address_space(1))) void*)((ptr) + (eoff)),         \
      (__attribute__((address_space(3))) void*)(lds + (ldsOff) + ldsW),        \
      16, 0, 0)
#define STAGE_TILE(BUF, eoff) do {                                             \
    STG(sA0, (BUF) * 16384, eoff);                                             \
    STG(sA1, (BUF) * 16384 + 8192, eoff);                                      \
    STG(sB0, 32768 + (BUF) * 16384, eoff);                                     \
    STG(sB1, 32768 + (BUF) * 16384 + 8192, eoff);                              \
  } while (0)

#define RDT(BUF) do {                                                          \
    _Pragma("unroll") for (int am = 0; am < 8; ++am)                           \
      af[am] = *(const bf16x8*)(lds + aOff + (BUF) * 16384 + am * 1024);       \
    _Pragma("unroll") for (int an = 0; an < 4; ++an)                           \
      bf[an] = *(const bf16x8*)(lds + bOff + (BUF) * 16384 + an * 1024);       \
  } while (0)

#define MFMAT do {                                                             \
    __builtin_amdgcn_s_setprio(1);                                             \
    _Pragma("unroll") for (int am = 0; am < 8; ++am)                           \
    _Pragma("unroll") for (int an = 0; an < 4; ++an)                           \
      acc[am][an] = __builtin_amdgcn_mfma_f32_16x16x32_bf16(                   \
          af[am], bf[an], acc[am][an], 0, 0, 0);                               \
    __builtin_amdgcn_s_setprio(0);                                             \
  } while (0)

#define SB __builtin_amdgcn_sched_barrier(0)
#define BAR __builtin_amdgcn_s_barrier()
#define VMC0 asm volatile("s_waitcnt vmcnt(0)" ::: "memory")

  f32x4 acc[8][4] = {};
  bf16x8 af[8], bf[4];

  // Prologue: stage tile 0 into buf0; drain; sync.
  STAGE_TILE(0, 0);
  SB;
  VMC0;
  BAR;

  // Main: 31 groups x 2 tiles = tiles 0..61 (stages 1..62).
  // body(t): RDT(t) [valid since barrier(t-1)]; STAGE(t+1) [WAR vs reads of
  // t-1: those preceded barrier(t-1)]; vmcnt(0); BAR [t+1 valid]; MFMA(t).
  for (int g = 0; g < 31; ++g) {
    RDT(0);
    STAGE_TILE(1, 32);
    SB; VMC0; BAR;
    MFMAT;

    RDT(1);
    STAGE_TILE(0, 64);
    SB; VMC0; BAR;
    MFMAT;

    sA0 += 64; sA1 += 64; sB0 += 64; sB1 += 64;
  }
  // tile 62 (buf0), stage 63 (buf1)
  RDT(0);
  STAGE_TILE(1, 32);
  SB; VMC0; BAR;
  MFMAT;
  // tile 63 (buf1), nothing in flight
  RDT(1);
  MFMAT;

#undef STG
#undef STAGE_TILE
#undef RDT
#undef MFMAT
#undef SB
#undef BAR
#undef VMC0

  const int crow0 = (lane >> 4) << 2;
  const int ccol = lane & 15;
  const int tcMask = (1 << tcShift) - 1;
#pragma unroll
  for (int am = 0; am < 8; ++am)
#pragma unroll
    for (int an = 0; an < 4; ++an) {
      const int col = bcol * 256 + wc * 64 + an * 16 + ccol;
#pragma unroll
      for (int j = 0; j < 4; ++j) {
        int r = brow * 256 + wr * 128 + am * 16 + crow0 + j;
        int orow = ((r >> tcShift) << 10) + t0 + (r & tcMask);
        if (BF16OUT)
          ((unsigned short*)Cv)[(size_t)orow * N + col] = f2bf(acc[am][an][j]);
        else
          ((float*)Cv)[(size_t)orow * N + col] = acc[am][an][j];
      }
    }
}

// ---------------------------------------------------------------------------
// WKV segmented scan (segment = TS steps), stabilized (aa,bb,pp) form.
// ---------------------------------------------------------------------------
__global__ void wkv_part(const float* __restrict__ time_decay,
                         const unsigned short* __restrict__ k,
                         const unsigned short* __restrict__ v,
                         float* __restrict__ paA, float* __restrict__ paB,
                         float* __restrict__ paP, int Tc) {
  int idx = blockIdx.x * blockDim.x + threadIdx.x;
  int c = idx & (CC - 1);
  int b = (idx >> 11) & (BB - 1);
  int s = idx >> 15;
  float w = -__expf(time_decay[c]);
  float aa = 0.f, bb = 0.f, pp = -1e38f;
  size_t base = ((size_t)b * Tc + s * TS) * CC + c;
  for (int t = 0; t < TS; ++t) {
    size_t off = base + (size_t)t * CC;
    float kt = bf2f(k[off]), vt = bf2f(v[off]);
    float ww2 = pp + w;
    float p2 = fmaxf(ww2, kt);
    float e1 = __expf(ww2 - p2), e2 = __expf(kt - p2);
    aa = e1 * aa + e2 * vt;
    bb = e1 * bb + e2;
    pp = p2;
  }
  paA[idx] = aa; paB[idx] = bb; paP[idx] = pp;
}

__global__ void wkv_comb(const float* __restrict__ time_decay,
                         const float* __restrict__ paA,
                         const float* __restrict__ paB,
                         const float* __restrict__ paP,
                         float* __restrict__ inA, float* __restrict__ inB,
                         float* __restrict__ inP,
                         float* __restrict__ state, int S, int t0) {
  int idx = blockIdx.x * blockDim.x + threadIdx.x;  // [0, BB*CC)
  int c = idx & (CC - 1);
  float w = -__expf(time_decay[c]);
  float wTs = w * (float)TS;
  float A, Bv, P;
  if (t0 == 0) { A = 0.f; Bv = 0.f; P = -1e38f; }
  else { A = state[idx]; Bv = state[32768 + idx]; P = state[65536 + idx]; }
  for (int s = 0; s < S; ++s) {
    size_t o = (size_t)s * 32768 + idx;
    inA[o] = A; inB[o] = Bv; inP[o] = P;
    float Pd = P + wTs;
    float Ps = paP[o];
    float Pn = fmaxf(Pd, Ps);
    float e1 = __expf(Pd - Pn), e2 = __expf(Ps - Pn);
    A = e1 * A + e2 * paA[o];
    Bv = e1 * Bv + e2 * paB[o];
    P = Pn;
  }
  state[idx] = A; state[32768 + idx] = Bv; state[65536 + idx] = P;
}

__global__ void wkv_out(const float* __restrict__ time_decay,
                        const float* __restrict__ time_first,
                        const unsigned short* __restrict__ k,
                        const unsigned short* __restrict__ v,
                        const unsigned short* __restrict__ r,
                        unsigned short* __restrict__ rwkv,
                        const float* __restrict__ inA,
                        const float* __restrict__ inB,
                        const float* __restrict__ inP, int Tc) {
  int idx = blockIdx.x * blockDim.x + threadIdx.x;
  int c = idx & (CC - 1);
  int b = (idx >> 11) & (BB - 1);
  int s = idx >> 15;
  float w = -__expf(time_decay[c]);
  float u = time_first[c];
  float aa = inA[idx], bb = inB[idx], pp = inP[idx];
  size_t base = ((size_t)b * Tc + s * TS) * CC + c;
  for (int t = 0; t < TS; ++t) {
    size_t off = base + (size_t)t * CC;
    float kt = bf2f(k[off]), vt = bf2f(v[off]);
    float ww = u + kt;
    float p = fmaxf(pp, ww);
    float e1 = __expf(pp - p), e2 = __expf(ww - p);
    float y = (e1 * aa + e2 * vt) / (e1 * bb + e2);
    float rr = bf2f(r[off]);
    float sr = 1.f / (1.f + __expf(-rr));
    rwkv[off] = f2bf(sr * y);
    float ww2 = pp + w;
    float p2 = fmaxf(ww2, kt);
    float e1b = __expf(ww2 - p2), e2b = __expf(kt - p2);
    aa = e1b * aa + e2b * vt;
    bb = e1b * bb + e2b;
    pp = p2;
  }
}

extern "C" void kernel_launch(void* const* d_in, const int* in_sizes, int n_in,
                              void* d_out, int out_size, void* d_ws,
                              size_t ws_size, hipStream_t stream) {
  const float* x          = (const float*)d_in[0];
  const float* time_decay = (const float*)d_in[1];
  const float* time_first = (const float*)d_in[2];
  const float* tmk        = (const float*)d_in[3];
  const float* tmv        = (const float*)d_in[4];
  const float* tmr        = (const float*)d_in[5];
  const float* key_w      = (const float*)d_in[6];
  const float* value_w    = (const float*)d_in[7];
  const float* rec_w      = (const float*)d_in[8];
  const float* out_w      = (const float*)d_in[9];
  float* out = (float*)d_out;

  const size_t WW = (size_t)CC * CC;
  const size_t wtBytes = 4 * WW * 2;               // 32 MB
  const size_t stBytes = 3 * (size_t)BB * CC * 4;  // 384 KB

  // per-chunk = BB*Tc*CC * (xk2+xv2+xr2+rbuf2+kbuf2+vbuf2) = 12 B/elem
  int Tc = 1024;
  while (Tc > 32) {
    size_t chunkBytes = (size_t)BB * Tc * CC * 12;
    if (wtBytes + stBytes + chunkBytes + 1024 <= ws_size) break;
    Tc >>= 1;
  }
  const int Mc = BB * Tc;
  const size_t NC = (size_t)Mc * CC;
  const int S = Tc / TS;

  char* p = (char*)d_ws;
  unsigned short* wk  = (unsigned short*)p; p += WW * 2;
  unsigned short* wv  = (unsigned short*)p; p += WW * 2;
  unsigned short* wrr = (unsigned short*)p; p += WW * 2;
  unsigned short* wo  = (unsigned short*)p; p += WW * 2;
  float* state        = (float*)p;          p += stBytes;
  unsigned short* kbuf= (unsigned short*)p; p += NC * 2;
  unsigned short* vbuf= (unsigned short*)p; p += NC * 2;
  unsigned short* xk  = (unsigned short*)p; p += NC * 2;  // aliased: rwkv
  unsigned short* xv  = (unsigned short*)p; p += NC * 2;  // aliased: scan bufs
  unsigned short* xr  = (unsigned short*)p; p += NC * 2;
  unsigned short* rbuf= (unsigned short*)p; p += NC * 2;
  unsigned short* rwkv = xk;

  const size_t SBt = (size_t)S * 32768;
  float* paA = (float*)xv;
  float* paB = paA + SBt;
  float* paP = paB + SBt;
  float* inA = paP + SBt;
  float* inB = inA + SBt;
  float* inP = inB + SBt;

  f2bf_all<<<2048, 256, 0, stream>>>(key_w, value_w, rec_w, out_w,
                                     wk, wv, wrr, wo, (int)(WW / 4));

  int tcShift = 0;
  while ((1 << tcShift) < Tc) ++tcShift;

  const int nwg = (Mc / 256) * (CC / 256);
  int mixBlocks = (Mc / 2 * (CC / 4) + 255) / 256;
  if (mixBlocks > 4096) mixBlocks = 4096;

  for (int t0 = 0; t0 < TT; t0 += Tc) {
    mix_kernel<<<mixBlocks, 256, 0, stream>>>(x, tmk, tmv, tmr, xk, xv, xr,
                                              t0, Tc);
    gemm256<true><<<nwg, 512, 0, stream>>>(xk, wk, kbuf, CC, CC, 10, 0);
    gemm256<true><<<nwg, 512, 0, stream>>>(xv, wv, vbuf, CC, CC, 10, 0);
    wkv_part<<<S * 128, 256, 0, stream>>>(time_decay, kbuf, vbuf,
                                          paA, paB, paP, Tc);
    gemm256<true><<<nwg, 512, 0, stream>>>(xr, wrr, rbuf, CC, CC, 10, 0);
    wkv_comb<<<128, 256, 0, stream>>>(time_decay, paA, paB, paP,
                                      inA, inB, inP, state, S, t0);
    wkv_out<<<S * 128, 256, 0, stream>>>(time_decay, time_first, kbuf, vbuf,
                                         rbuf, rwkv, inA, inB, inP, Tc);
    gemm256<false><<<nwg, 512, 0, stream>>>(rwkv, wo, out, CC, CC,
                                            tcShift, t0);
  }
}

// Round 17
// 701.337 us; speedup vs baseline: 1.2775x; 1.2775x over previous
//
#include <hip/hip_runtime.h>
#include <hip/hip_bf16.h>

#define BB 16
#define TT 1024
#define CC 2048
#define TS 32   // wkv scan segment length

typedef __attribute__((ext_vector_type(4))) float f32x4;
typedef __attribute__((ext_vector_type(8))) short bf16x8;

__device__ __forceinline__ unsigned short f2bf(float f) {
  union { float f; unsigned u; } x; x.f = f;
  unsigned r = x.u + 0x7fffu + ((x.u >> 16) & 1u);
  return (unsigned short)(r >> 16);
}
__device__ __forceinline__ float bf2f(unsigned short u) {
  union { unsigned u; float f; } x; x.u = ((unsigned)u) << 16;
  return x.f;
}
__device__ __forceinline__ float bf2f_lo(unsigned u) {
  union { unsigned u; float f; } x; x.u = u << 16;
  return x.f;
}
__device__ __forceinline__ float bf2f_hi(unsigned u) {
  union { unsigned u; float f; } x; x.u = u & 0xffff0000u;
  return x.f;
}

__device__ __forceinline__ ushort4 mix4(float4 a, float4 b, float4 m) {
  ushort4 o;
  o.x = f2bf(a.x * m.x + b.x * (1.f - m.x));
  o.y = f2bf(a.y * m.y + b.y * (1.f - m.y));
  o.z = f2bf(a.z * m.z + b.z * (1.f - m.z));
  o.w = f2bf(a.w * m.w + b.w * (1.f - m.w));
  return o;
}

__global__ void f2bf_all(const float* __restrict__ w0, const float* __restrict__ w1,
                         const float* __restrict__ w2, const float* __restrict__ w3,
                         unsigned short* __restrict__ o0, unsigned short* __restrict__ o1,
                         unsigned short* __restrict__ o2, unsigned short* __restrict__ o3,
                         int n4each) {
  const float* ws[4] = {w0, w1, w2, w3};
  unsigned short* os[4] = {o0, o1, o2, o3};
  int total = 4 * n4each;
  for (int i = blockIdx.x * blockDim.x + threadIdx.x; i < total;
       i += gridDim.x * blockDim.x) {
    int seg = i / n4each, j = i - seg * n4each;
    float4 v = ((const float4*)ws[seg])[j];
    ushort4 o;
    o.x = f2bf(v.x); o.y = f2bf(v.y); o.z = f2bf(v.z); o.w = f2bf(v.w);
    ((ushort4*)os[seg])[j] = o;
  }
}

// time-shift mix, ROW-PAIRED (R15): each thread produces t=2j and 2j+1.
__global__ void mix_kernel(const float* __restrict__ x,
                           const float* __restrict__ tmk,
                           const float* __restrict__ tmv,
                           const float* __restrict__ tmr,
                           unsigned short* __restrict__ xk,
                           unsigned short* __restrict__ xv,
                           unsigned short* __restrict__ xr,
                           int t0, int Tc) {
  const int C4 = CC / 4;
  const int halfT = Tc >> 1;
  const int total = BB * halfT * C4;
  for (int g = blockIdx.x * blockDim.x + threadIdx.x; g < total;
       g += gridDim.x * blockDim.x) {
    int cg = g % C4;
    int rp = g / C4;
    int j = rp % halfT;
    int b = rp / halfT;
    int tl = 2 * j;
    int t = t0 + tl;
    size_t gidx0 = (size_t)(b * TT + t) * C4 + cg;
    float4 x0 = ((const float4*)x)[gidx0];
    float4 x1 = ((const float4*)x)[gidx0 + C4];
    float4 xm = make_float4(0.f, 0.f, 0.f, 0.f);
    if (t > 0) xm = ((const float4*)x)[gidx0 - C4];
    float4 mk = ((const float4*)tmk)[cg];
    float4 mv = ((const float4*)tmv)[cg];
    float4 mr = ((const float4*)tmr)[cg];
    size_t o0 = (size_t)(b * Tc + tl) * C4 + cg;
    ((ushort4*)xk)[o0] = mix4(x0, xm, mk);
    ((ushort4*)xv)[o0] = mix4(x0, xm, mv);
    ((ushort4*)xr)[o0] = mix4(x0, xm, mr);
    ((ushort4*)xk)[o0 + C4] = mix4(x1, x0, mk);
    ((ushort4*)xv)[o0 + C4] = mix4(x1, x0, mv);
    ((ushort4*)xr)[o0 + C4] = mix4(x1, x0, mr);
  }
}

// ---------------------------------------------------------------------------
// 256x256 GEMM, BK=32, 8 waves (2x4), QUAD-buffered LDS (4 x 32KB),
// SPLIT IN-PLACE RELOAD (R13/R15, converged best: 133us / ~1030 TF).
// 10 schedule/occupancy variants bracketed this structure (133-145us for
// in-budget ones; ping-pong/2-block variants regressed via spill or shared
// staging-path contention). Keep verbatim.
// ---------------------------------------------------------------------------
template<bool BF16OUT>
__global__ __launch_bounds__(512, 2)
void gemm256(const unsigned short* __restrict__ A,
             const unsigned short* __restrict__ B,
             void* __restrict__ Cv, int N, int K, int tcShift, int t0) {
  __shared__ __align__(1024) unsigned char lds[131072];
  const int tid = threadIdx.x;
  const int lane = tid & 63;
  const int wid = tid >> 6;
  const int wr = wid >> 2;   // 0..1
  const int wc = wid & 3;    // 0..3

  const int nwg = gridDim.x;
  const int cpx = nwg >> 3;
  const int bid = blockIdx.x;
  const int wg = (bid & 7) * cpx + (bid >> 3);
  const int bcolN = N >> 8;
  const int brow = wg / bcolN;
  const int bcol = wg % bcolN;

  const int strow = tid >> 2;                                   // 0..127
  const int scelem = (((tid & 3) ^ ((tid >> 3) & 3)) << 3);     // elems
  const unsigned short* sA0 = A + (size_t)(brow * 256 + strow) * K + scelem;
  const unsigned short* sA1 = A + (size_t)(brow * 256 + 128 + strow) * K + scelem;
  const unsigned short* sB0 = B + (size_t)(bcol * 256 + strow) * K + scelem;
  const unsigned short* sB1 = B + (size_t)(bcol * 256 + 128 + strow) * K + scelem;

  const int frow = lane & 15;
  const int fhi = (lane >> 4) << 4;
  const int fsw = ((frow >> 1) & 3) << 4;
  const int aOff = (wr * 128 + frow) * 64 + (fhi ^ fsw);
  const int bOff = 65536 + (wc * 64 + frow) * 64 + (fhi ^ fsw);
  const int ldsW = wid * 1024;

#define STG(ptr, ldsOff, eoff)                                                 \
  __builtin_amdgcn_global_load_lds(                                            \
      (const __attribute__((address_space(1))) void*)((ptr) + (eoff)),         \
      (__attribute__((address_space(3))) void*)(lds + (ldsOff) + ldsW),        \
      16, 0, 0)
#define STAGE_TILE(BUF, eoff) do {                                             \
    STG(sA0, (BUF) * 16384, eoff);                                             \
    STG(sA1, (BUF) * 16384 + 8192, eoff);                                      \
    STG(sB0, 65536 + (BUF) * 16384, eoff);                                     \
    STG(sB1, 65536 + (BUF) * 16384 + 8192, eoff);                              \
  } while (0)

#define RD_A_HALF(BUF, BASE) do {                                              \
    _Pragma("unroll") for (int m = 0; m < 4; ++m)                              \
      af[(BASE) + m] = *(const bf16x8*)(lds + aOff + (BUF) * 16384 +           \
                                        ((BASE) + m) * 1024);                  \
  } while (0)
#define RD_B(BUF) do {                                                         \
    _Pragma("unroll") for (int an = 0; an < 4; ++an)                           \
      bf[an] = *(const bf16x8*)(lds + bOff + (BUF) * 16384 + an * 1024);       \
  } while (0)

#define MFMA_HALF(BASE) do {                                                   \
    __builtin_amdgcn_s_setprio(1);                                             \
    _Pragma("unroll") for (int m = 0; m < 4; ++m)                              \
    _Pragma("unroll") for (int an = 0; an < 4; ++an)                           \
      acc[(BASE) + m][an] = __builtin_amdgcn_mfma_f32_16x16x32_bf16(           \
          af[(BASE) + m], bf[an], acc[(BASE) + m][an], 0, 0, 0);               \
    __builtin_amdgcn_s_setprio(0);                                             \
  } while (0)

#define SB __builtin_amdgcn_sched_barrier(0)
#define BAR __builtin_amdgcn_s_barrier()
#define VMC(n) asm volatile("s_waitcnt vmcnt(" #n ")" ::: "memory")

  f32x4 acc[8][4] = {};
  bf16x8 af[8], bf[4];

  STAGE_TILE(0, 0);
  STAGE_TILE(1, 32);
  STAGE_TILE(2, 64);
  SB;
  VMC(4);
  BAR;
  SB;
  RD_A_HALF(0, 0); RD_A_HALF(0, 4); RD_B(0);

  for (int g = 0; g < 15; ++g) {
#define TILE_BODY(J)                                                           \
    STAGE_TILE((J + 3) & 3, (3 + J) * 32);                                     \
    MFMA_HALF(0);                                                              \
    RD_A_HALF((J + 1) & 3, 0);                                                 \
    MFMA_HALF(4);                                                              \
    RD_A_HALF((J + 1) & 3, 4);                                                 \
    SB;                                                                        \
    VMC(4);                                                                    \
    BAR;                                                                       \
    SB;                                                                        \
    RD_B((J + 1) & 3);
    TILE_BODY(0)
    TILE_BODY(1)
    TILE_BODY(2)
    TILE_BODY(3)
#undef TILE_BODY
    sA0 += 128; sA1 += 128; sB0 += 128; sB1 += 128;
  }

  STAGE_TILE(3, 96);
  MFMA_HALF(0);
  RD_A_HALF(1, 0);
  MFMA_HALF(4);
  RD_A_HALF(1, 4);
  SB; VMC(4); BAR; SB;
  RD_B(1);
  MFMA_HALF(0);
  RD_A_HALF(2, 0);
  MFMA_HALF(4);
  RD_A_HALF(2, 4);
  SB; VMC(0); BAR; SB;
  RD_B(2);
  MFMA_HALF(0);
  RD_A_HALF(3, 0);
  MFMA_HALF(4);
  RD_A_HALF(3, 4);
  RD_B(3);
  MFMA_HALF(0);
  MFMA_HALF(4);

#undef STG
#undef STAGE_TILE
#undef RD_A_HALF
#undef RD_B
#undef MFMA_HALF
#undef SB
#undef BAR
#undef VMC

  const int crow0 = (lane >> 4) << 2;
  const int ccol = lane & 15;
  const int tcMask = (1 << tcShift) - 1;
#pragma unroll
  for (int am = 0; am < 8; ++am)
#pragma unroll
    for (int an = 0; an < 4; ++an) {
      const int col = bcol * 256 + wc * 64 + an * 16 + ccol;
#pragma unroll
      for (int j = 0; j < 4; ++j) {
        int r = brow * 256 + wr * 128 + am * 16 + crow0 + j;
        int orow = ((r >> tcShift) << 10) + t0 + (r & tcMask);
        if (BF16OUT)
          ((unsigned short*)Cv)[(size_t)orow * N + col] = f2bf(acc[am][an][j]);
        else
          ((float*)Cv)[(size_t)orow * N + col] = acc[am][an][j];
      }
    }
}

// ---------------------------------------------------------------------------
// WKV segmented scan, CHANNEL-PAIRED (G13): each thread owns channels
// (2c, 2c+1) -> k/v/r loads and rwkv store are 4B/lane uint accesses
// (full 256B/wave coalescing vs 2B/lane scalar bf16).
// ---------------------------------------------------------------------------
__global__ void wkv_part(const float* __restrict__ time_decay,
                         const unsigned short* __restrict__ k,
                         const unsigned short* __restrict__ v,
                         float* __restrict__ paA, float* __restrict__ paB,
                         float* __restrict__ paP, int Tc) {
  int idx = blockIdx.x * blockDim.x + threadIdx.x;  // [0, S*BB*1024)
  int c = (idx & 1023) << 1;
  int b = (idx >> 10) & (BB - 1);
  int s = idx >> 14;
  float w0 = -__expf(time_decay[c]);
  float w1 = -__expf(time_decay[c + 1]);
  float aa0 = 0.f, bb0 = 0.f, pp0 = -1e38f;
  float aa1 = 0.f, bb1 = 0.f, pp1 = -1e38f;
  size_t base = ((size_t)b * Tc + s * TS) * CC + c;
  for (int t = 0; t < TS; ++t) {
    size_t off = base + (size_t)t * CC;
    unsigned ku = *(const unsigned*)(k + off);
    unsigned vu = *(const unsigned*)(v + off);
    float kt0 = bf2f_lo(ku), kt1 = bf2f_hi(ku);
    float vt0 = bf2f_lo(vu), vt1 = bf2f_hi(vu);
    float ww = pp0 + w0;
    float p2 = fmaxf(ww, kt0);
    float e1 = __expf(ww - p2), e2 = __expf(kt0 - p2);
    aa0 = e1 * aa0 + e2 * vt0; bb0 = e1 * bb0 + e2; pp0 = p2;
    ww = pp1 + w1;
    p2 = fmaxf(ww, kt1);
    e1 = __expf(ww - p2); e2 = __expf(kt1 - p2);
    aa1 = e1 * aa1 + e2 * vt1; bb1 = e1 * bb1 + e2; pp1 = p2;
  }
  size_t o = (size_t)s * 32768 + b * 2048 + c;
  paA[o] = aa0; paA[o + 1] = aa1;
  paB[o] = bb0; paB[o + 1] = bb1;
  paP[o] = pp0; paP[o + 1] = pp1;
}

__global__ void wkv_comb(const float* __restrict__ time_decay,
                         const float* __restrict__ paA,
                         const float* __restrict__ paB,
                         const float* __restrict__ paP,
                         float* __restrict__ inA, float* __restrict__ inB,
                         float* __restrict__ inP,
                         float* __restrict__ state, int S, int t0) {
  int idx = blockIdx.x * blockDim.x + threadIdx.x;  // [0, BB*CC)
  int c = idx & (CC - 1);
  float w = -__expf(time_decay[c]);
  float wTs = w * (float)TS;
  float A, Bv, P;
  if (t0 == 0) { A = 0.f; Bv = 0.f; P = -1e38f; }
  else { A = state[idx]; Bv = state[32768 + idx]; P = state[65536 + idx]; }
  for (int s = 0; s < S; ++s) {
    size_t o = (size_t)s * 32768 + idx;
    inA[o] = A; inB[o] = Bv; inP[o] = P;
    float Pd = P + wTs;
    float Ps = paP[o];
    float Pn = fmaxf(Pd, Ps);
    float e1 = __expf(Pd - Pn), e2 = __expf(Ps - Pn);
    A = e1 * A + e2 * paA[o];
    Bv = e1 * Bv + e2 * paB[o];
    P = Pn;
  }
  state[idx] = A; state[32768 + idx] = Bv; state[65536 + idx] = P;
}

__global__ void wkv_out(const float* __restrict__ time_decay,
                        const float* __restrict__ time_first,
                        const unsigned short* __restrict__ k,
                        const unsigned short* __restrict__ v,
                        const unsigned short* __restrict__ r,
                        unsigned short* __restrict__ rwkv,
                        const float* __restrict__ inA,
                        const float* __restrict__ inB,
                        const float* __restrict__ inP, int Tc) {
  int idx = blockIdx.x * blockDim.x + threadIdx.x;  // [0, S*BB*1024)
  int c = (idx & 1023) << 1;
  int b = (idx >> 10) & (BB - 1);
  int s = idx >> 14;
  float w0 = -__expf(time_decay[c]);
  float w1 = -__expf(time_decay[c + 1]);
  float u0 = time_first[c], u1 = time_first[c + 1];
  size_t si = (size_t)s * 32768 + b * 2048 + c;
  float aa0 = inA[si], bb0 = inB[si], pp0 = inP[si];
  float aa1 = inA[si + 1], bb1 = inB[si + 1], pp1 = inP[si + 1];
  size_t base = ((size_t)b * Tc + s * TS) * CC + c;
  for (int t = 0; t < TS; ++t) {
    size_t off = base + (size_t)t * CC;
    unsigned ku = *(const unsigned*)(k + off);
    unsigned vu = *(const unsigned*)(v + off);
    unsigned ru = *(const unsigned*)(r + off);
    float kt0 = bf2f_lo(ku), kt1 = bf2f_hi(ku);
    float vt0 = bf2f_lo(vu), vt1 = bf2f_hi(vu);
    float rr0 = bf2f_lo(ru), rr1 = bf2f_hi(ru);
    // channel 0
    float ww = u0 + kt0;
    float p = fmaxf(pp0, ww);
    float e1 = __expf(pp0 - p), e2 = __expf(ww - p);
    float y0 = (e1 * aa0 + e2 * vt0) / (e1 * bb0 + e2);
    float sr0 = 1.f / (1.f + __expf(-rr0));
    float ww2 = pp0 + w0;
    float p2 = fmaxf(ww2, kt0);
    float e1b = __expf(ww2 - p2), e2b = __expf(kt0 - p2);
    aa0 = e1b * aa0 + e2b * vt0; bb0 = e1b * bb0 + e2b; pp0 = p2;
    // channel 1
    ww = u1 + kt1;
    p = fmaxf(pp1, ww);
    e1 = __expf(pp1 - p); e2 = __expf(ww - p);
    float y1 = (e1 * aa1 + e2 * vt1) / (e1 * bb1 + e2);
    float sr1 = 1.f / (1.f + __expf(-rr1));
    ww2 = pp1 + w1;
    p2 = fmaxf(ww2, kt1);
    e1b = __expf(ww2 - p2); e2b = __expf(kt1 - p2);
    aa1 = e1b * aa1 + e2b * vt1; bb1 = e1b * bb1 + e2b; pp1 = p2;
    unsigned out = (unsigned)f2bf(sr0 * y0) | ((unsigned)f2bf(sr1 * y1) << 16);
    *(unsigned*)(rwkv + off) = out;
  }
}

extern "C" void kernel_launch(void* const* d_in, const int* in_sizes, int n_in,
                              void* d_out, int out_size, void* d_ws,
                              size_t ws_size, hipStream_t stream) {
  const float* x          = (const float*)d_in[0];
  const float* time_decay = (const float*)d_in[1];
  const float* time_first = (const float*)d_in[2];
  const float* tmk        = (const float*)d_in[3];
  const float* tmv        = (const float*)d_in[4];
  const float* tmr        = (const float*)d_in[5];
  const float* key_w      = (const float*)d_in[6];
  const float* value_w    = (const float*)d_in[7];
  const float* rec_w      = (const float*)d_in[8];
  const float* out_w      = (const float*)d_in[9];
  float* out = (float*)d_out;

  const size_t WW = (size_t)CC * CC;
  const size_t wtBytes = 4 * WW * 2;               // 32 MB
  const size_t stBytes = 3 * (size_t)BB * CC * 4;  // 384 KB

  int Tc = 1024;
  while (Tc > 32) {
    size_t chunkBytes = (size_t)BB * Tc * CC * 12;
    if (wtBytes + stBytes + chunkBytes + 1024 <= ws_size) break;
    Tc >>= 1;
  }
  const int Mc = BB * Tc;
  const size_t NC = (size_t)Mc * CC;
  const int S = Tc / TS;

  char* p = (char*)d_ws;
  unsigned short* wk  = (unsigned short*)p; p += WW * 2;
  unsigned short* wv  = (unsigned short*)p; p += WW * 2;
  unsigned short* wrr = (unsigned short*)p; p += WW * 2;
  unsigned short* wo  = (unsigned short*)p; p += WW * 2;
  float* state        = (float*)p;          p += stBytes;
  unsigned short* kbuf= (unsigned short*)p; p += NC * 2;
  unsigned short* vbuf= (unsigned short*)p; p += NC * 2;
  unsigned short* xk  = (unsigned short*)p; p += NC * 2;  // aliased: rwkv
  unsigned short* xv  = (unsigned short*)p; p += NC * 2;  // aliased: scan bufs
  unsigned short* xr  = (unsigned short*)p; p += NC * 2;
  unsigned short* rbuf= (unsigned short*)p; p += NC * 2;
  unsigned short* rwkv = xk;

  const size_t SBt = (size_t)S * 32768;
  float* paA = (float*)xv;
  float* paB = paA + SBt;
  float* paP = paB + SBt;
  float* inA = paP + SBt;
  float* inB = inA + SBt;
  float* inP = inB + SBt;

  f2bf_all<<<2048, 256, 0, stream>>>(key_w, value_w, rec_w, out_w,
                                     wk, wv, wrr, wo, (int)(WW / 4));

  int tcShift = 0;
  while ((1 << tcShift) < Tc) ++tcShift;

  const int nwg = (Mc / 256) * (CC / 256);
  int mixBlocks = (Mc / 2 * (CC / 4) + 255) / 256;
  if (mixBlocks > 4096) mixBlocks = 4096;

  for (int t0 = 0; t0 < TT; t0 += Tc) {
    mix_kernel<<<mixBlocks, 256, 0, stream>>>(x, tmk, tmv, tmr, xk, xv, xr,
                                              t0, Tc);
    gemm256<true><<<nwg, 512, 0, stream>>>(xk, wk, kbuf, CC, CC, 10, 0);
    gemm256<true><<<nwg, 512, 0, stream>>>(xv, wv, vbuf, CC, CC, 10, 0);
    wkv_part<<<S * 64, 256, 0, stream>>>(time_decay, kbuf, vbuf,
                                         paA, paB, paP, Tc);
    gemm256<true><<<nwg, 512, 0, stream>>>(xr, wrr, rbuf, CC, CC, 10, 0);
    wkv_comb<<<128, 256, 0, stream>>>(time_decay, paA, paB, paP,
                                      inA, inB, inP, state, S, t0);
    wkv_out<<<S * 64, 256, 0, stream>>>(time_decay, time_first, kbuf, vbuf,
                                        rbuf, rwkv, inA, inB, inP, Tc);
    gemm256<false><<<nwg, 512, 0, stream>>>(rwkv, wo, out, CC, CC,
                                            tcShift, t0);
  }
}

// Round 18
// 688.630 us; speedup vs baseline: 1.3011x; 1.0185x over previous
//
#include <hip/hip_runtime.h>
#include <hip/hip_bf16.h>

#define BB 16
#define TT 1024
#define CC 2048
#define TS 32   // wkv scan segment length

typedef __attribute__((ext_vector_type(4))) float f32x4;
typedef __attribute__((ext_vector_type(8))) short bf16x8;

__device__ __forceinline__ unsigned short f2bf(float f) {
  union { float f; unsigned u; } x; x.f = f;
  unsigned r = x.u + 0x7fffu + ((x.u >> 16) & 1u);
  return (unsigned short)(r >> 16);
}
__device__ __forceinline__ float bf2f(unsigned short u) {
  union { unsigned u; float f; } x; x.u = ((unsigned)u) << 16;
  return x.f;
}
__device__ __forceinline__ float bf2f_lo(unsigned u) {
  union { unsigned u; float f; } x; x.u = u << 16;
  return x.f;
}
__device__ __forceinline__ float bf2f_hi(unsigned u) {
  union { unsigned u; float f; } x; x.u = u & 0xffff0000u;
  return x.f;
}

__device__ __forceinline__ ushort4 mix4(float4 a, float4 b, float4 m) {
  ushort4 o;
  o.x = f2bf(a.x * m.x + b.x * (1.f - m.x));
  o.y = f2bf(a.y * m.y + b.y * (1.f - m.y));
  o.z = f2bf(a.z * m.z + b.z * (1.f - m.z));
  o.w = f2bf(a.w * m.w + b.w * (1.f - m.w));
  return o;
}

__global__ void f2bf_all(const float* __restrict__ w0, const float* __restrict__ w1,
                         const float* __restrict__ w2, const float* __restrict__ w3,
                         unsigned short* __restrict__ o0, unsigned short* __restrict__ o1,
                         unsigned short* __restrict__ o2, unsigned short* __restrict__ o3,
                         int n4each) {
  const float* ws[4] = {w0, w1, w2, w3};
  unsigned short* os[4] = {o0, o1, o2, o3};
  int total = 4 * n4each;
  for (int i = blockIdx.x * blockDim.x + threadIdx.x; i < total;
       i += gridDim.x * blockDim.x) {
    int seg = i / n4each, j = i - seg * n4each;
    float4 v = ((const float4*)ws[seg])[j];
    ushort4 o;
    o.x = f2bf(v.x); o.y = f2bf(v.y); o.z = f2bf(v.z); o.w = f2bf(v.w);
    ((ushort4*)os[seg])[j] = o;
  }
}

// time-shift mix, ROW-PAIRED (R15): each thread produces t=2j and 2j+1.
__global__ void mix_kernel(const float* __restrict__ x,
                           const float* __restrict__ tmk,
                           const float* __restrict__ tmv,
                           const float* __restrict__ tmr,
                           unsigned short* __restrict__ xk,
                           unsigned short* __restrict__ xv,
                           unsigned short* __restrict__ xr,
                           int t0, int Tc) {
  const int C4 = CC / 4;
  const int halfT = Tc >> 1;
  const int total = BB * halfT * C4;
  for (int g = blockIdx.x * blockDim.x + threadIdx.x; g < total;
       g += gridDim.x * blockDim.x) {
    int cg = g % C4;
    int rp = g / C4;
    int j = rp % halfT;
    int b = rp / halfT;
    int tl = 2 * j;
    int t = t0 + tl;
    size_t gidx0 = (size_t)(b * TT + t) * C4 + cg;
    float4 x0 = ((const float4*)x)[gidx0];
    float4 x1 = ((const float4*)x)[gidx0 + C4];
    float4 xm = make_float4(0.f, 0.f, 0.f, 0.f);
    if (t > 0) xm = ((const float4*)x)[gidx0 - C4];
    float4 mk = ((const float4*)tmk)[cg];
    float4 mv = ((const float4*)tmv)[cg];
    float4 mr = ((const float4*)tmr)[cg];
    size_t o0 = (size_t)(b * Tc + tl) * C4 + cg;
    ((ushort4*)xk)[o0] = mix4(x0, xm, mk);
    ((ushort4*)xv)[o0] = mix4(x0, xm, mv);
    ((ushort4*)xr)[o0] = mix4(x0, xm, mr);
    ((ushort4*)xk)[o0 + C4] = mix4(x1, x0, mk);
    ((ushort4*)xv)[o0 + C4] = mix4(x1, x0, mv);
    ((ushort4*)xr)[o0 + C4] = mix4(x1, x0, mr);
  }
}

// ---------------------------------------------------------------------------
// 256x256 GEMM, BK=32, 8 waves (2x4), QUAD-buffered LDS (4 x 32KB),
// SPLIT IN-PLACE RELOAD (R13/R15, converged best: 133us / ~1030 TF).
// FUSE3=1: grid covers 3 stacked problems {xk*wk->kbuf, xv*wv->vbuf,
// xr*wrr->rbuf}; which = brow>>6 selects bases via stride-add (wave-uniform,
// no divergence). One dispatch = one block-tail instead of three + 2 fewer
// launch gaps. All bases contiguous in workspace: A +which*sA, B +which*WW,
// C +which*sC.
// ---------------------------------------------------------------------------
template<bool BF16OUT, bool FUSE3>
__global__ __launch_bounds__(512, 2)
void gemm256(const unsigned short* __restrict__ A,
             const unsigned short* __restrict__ B,
             void* __restrict__ Cv, int N, int K, int tcShift, int t0,
             size_t sA, size_t sC) {
  __shared__ __align__(1024) unsigned char lds[131072];
  const int tid = threadIdx.x;
  const int lane = tid & 63;
  const int wid = tid >> 6;
  const int wr = wid >> 2;   // 0..1
  const int wc = wid & 3;    // 0..3

  const int nwg = gridDim.x;
  const int cpx = nwg >> 3;
  const int bid = blockIdx.x;
  const int wg = (bid & 7) * cpx + (bid >> 3);
  const int bcolN = N >> 8;
  int brow = wg / bcolN;
  const int bcol = wg % bcolN;

  const unsigned short* Ab = A;
  const unsigned short* Bb = B;
  unsigned short* Cb16 = (unsigned short*)Cv;
  float* Cb32 = (float*)Cv;
  if (FUSE3) {
    const int which = brow >> 6;
    brow &= 63;
    Ab += (size_t)which * sA;
    Bb += (size_t)which * ((size_t)CC * CC);
    Cb16 += (size_t)which * sC;
  }

  const int strow = tid >> 2;                                   // 0..127
  const int scelem = (((tid & 3) ^ ((tid >> 3) & 3)) << 3);     // elems
  const unsigned short* sA0 = Ab + (size_t)(brow * 256 + strow) * K + scelem;
  const unsigned short* sA1 = Ab + (size_t)(brow * 256 + 128 + strow) * K + scelem;
  const unsigned short* sB0 = Bb + (size_t)(bcol * 256 + strow) * K + scelem;
  const unsigned short* sB1 = Bb + (size_t)(bcol * 256 + 128 + strow) * K + scelem;

  const int frow = lane & 15;
  const int fhi = (lane >> 4) << 4;
  const int fsw = ((frow >> 1) & 3) << 4;
  const int aOff = (wr * 128 + frow) * 64 + (fhi ^ fsw);
  const int bOff = 65536 + (wc * 64 + frow) * 64 + (fhi ^ fsw);
  const int ldsW = wid * 1024;

#define STG(ptr, ldsOff, eoff)                                                 \
  __builtin_amdgcn_global_load_lds(                                            \
      (const __attribute__((address_space(1))) void*)((ptr) + (eoff)),         \
      (__attribute__((address_space(3))) void*)(lds + (ldsOff) + ldsW),        \
      16, 0, 0)
#define STAGE_TILE(BUF, eoff) do {                                             \
    STG(sA0, (BUF) * 16384, eoff);                                             \
    STG(sA1, (BUF) * 16384 + 8192, eoff);                                      \
    STG(sB0, 65536 + (BUF) * 16384, eoff);                                     \
    STG(sB1, 65536 + (BUF) * 16384 + 8192, eoff);                              \
  } while (0)

#define RD_A_HALF(BUF, BASE) do {                                              \
    _Pragma("unroll") for (int m = 0; m < 4; ++m)                              \
      af[(BASE) + m] = *(const bf16x8*)(lds + aOff + (BUF) * 16384 +           \
                                        ((BASE) + m) * 1024);                  \
  } while (0)
#define RD_B(BUF) do {                                                         \
    _Pragma("unroll") for (int an = 0; an < 4; ++an)                           \
      bf[an] = *(const bf16x8*)(lds + bOff + (BUF) * 16384 + an * 1024);       \
  } while (0)

#define MFMA_HALF(BASE) do {                                                   \
    __builtin_amdgcn_s_setprio(1);                                             \
    _Pragma("unroll") for (int m = 0; m < 4; ++m)                              \
    _Pragma("unroll") for (int an = 0; an < 4; ++an)                           \
      acc[(BASE) + m][an] = __builtin_amdgcn_mfma_f32_16x16x32_bf16(           \
          af[(BASE) + m], bf[an], acc[(BASE) + m][an], 0, 0, 0);               \
    __builtin_amdgcn_s_setprio(0);                                             \
  } while (0)

#define SB __builtin_amdgcn_sched_barrier(0)
#define BAR __builtin_amdgcn_s_barrier()
#define VMC(n) asm volatile("s_waitcnt vmcnt(" #n ")" ::: "memory")

  f32x4 acc[8][4] = {};
  bf16x8 af[8], bf[4];

  STAGE_TILE(0, 0);
  STAGE_TILE(1, 32);
  STAGE_TILE(2, 64);
  SB;
  VMC(4);
  BAR;
  SB;
  RD_A_HALF(0, 0); RD_A_HALF(0, 4); RD_B(0);

  for (int g = 0; g < 15; ++g) {
#define TILE_BODY(J)                                                           \
    STAGE_TILE((J + 3) & 3, (3 + J) * 32);                                     \
    MFMA_HALF(0);                                                              \
    RD_A_HALF((J + 1) & 3, 0);                                                 \
    MFMA_HALF(4);                                                              \
    RD_A_HALF((J + 1) & 3, 4);                                                 \
    SB;                                                                        \
    VMC(4);                                                                    \
    BAR;                                                                       \
    SB;                                                                        \
    RD_B((J + 1) & 3);
    TILE_BODY(0)
    TILE_BODY(1)
    TILE_BODY(2)
    TILE_BODY(3)
#undef TILE_BODY
    sA0 += 128; sA1 += 128; sB0 += 128; sB1 += 128;
  }

  STAGE_TILE(3, 96);
  MFMA_HALF(0);
  RD_A_HALF(1, 0);
  MFMA_HALF(4);
  RD_A_HALF(1, 4);
  SB; VMC(4); BAR; SB;
  RD_B(1);
  MFMA_HALF(0);
  RD_A_HALF(2, 0);
  MFMA_HALF(4);
  RD_A_HALF(2, 4);
  SB; VMC(0); BAR; SB;
  RD_B(2);
  MFMA_HALF(0);
  RD_A_HALF(3, 0);
  MFMA_HALF(4);
  RD_A_HALF(3, 4);
  RD_B(3);
  MFMA_HALF(0);
  MFMA_HALF(4);

#undef STG
#undef STAGE_TILE
#undef RD_A_HALF
#undef RD_B
#undef MFMA_HALF
#undef SB
#undef BAR
#undef VMC

  const int crow0 = (lane >> 4) << 2;
  const int ccol = lane & 15;
  const int tcMask = (1 << tcShift) - 1;
#pragma unroll
  for (int am = 0; am < 8; ++am)
#pragma unroll
    for (int an = 0; an < 4; ++an) {
      const int col = bcol * 256 + wc * 64 + an * 16 + ccol;
#pragma unroll
      for (int j = 0; j < 4; ++j) {
        int r = brow * 256 + wr * 128 + am * 16 + crow0 + j;
        int orow = ((r >> tcShift) << 10) + t0 + (r & tcMask);
        if (BF16OUT)
          Cb16[(size_t)orow * N + col] = f2bf(acc[am][an][j]);
        else
          Cb32[(size_t)orow * N + col] = acc[am][an][j];
      }
    }
}

// ---------------------------------------------------------------------------
// WKV segmented scan, CHANNEL-PAIRED (R17): thread owns channels (2c, 2c+1).
// ---------------------------------------------------------------------------
__global__ void wkv_part(const float* __restrict__ time_decay,
                         const unsigned short* __restrict__ k,
                         const unsigned short* __restrict__ v,
                         float* __restrict__ paA, float* __restrict__ paB,
                         float* __restrict__ paP, int Tc) {
  int idx = blockIdx.x * blockDim.x + threadIdx.x;
  int c = (idx & 1023) << 1;
  int b = (idx >> 10) & (BB - 1);
  int s = idx >> 14;
  float w0 = -__expf(time_decay[c]);
  float w1 = -__expf(time_decay[c + 1]);
  float aa0 = 0.f, bb0 = 0.f, pp0 = -1e38f;
  float aa1 = 0.f, bb1 = 0.f, pp1 = -1e38f;
  size_t base = ((size_t)b * Tc + s * TS) * CC + c;
  for (int t = 0; t < TS; ++t) {
    size_t off = base + (size_t)t * CC;
    unsigned ku = *(const unsigned*)(k + off);
    unsigned vu = *(const unsigned*)(v + off);
    float kt0 = bf2f_lo(ku), kt1 = bf2f_hi(ku);
    float vt0 = bf2f_lo(vu), vt1 = bf2f_hi(vu);
    float ww = pp0 + w0;
    float p2 = fmaxf(ww, kt0);
    float e1 = __expf(ww - p2), e2 = __expf(kt0 - p2);
    aa0 = e1 * aa0 + e2 * vt0; bb0 = e1 * bb0 + e2; pp0 = p2;
    ww = pp1 + w1;
    p2 = fmaxf(ww, kt1);
    e1 = __expf(ww - p2); e2 = __expf(kt1 - p2);
    aa1 = e1 * aa1 + e2 * vt1; bb1 = e1 * bb1 + e2; pp1 = p2;
  }
  size_t o = (size_t)s * 32768 + b * 2048 + c;
  paA[o] = aa0; paA[o + 1] = aa1;
  paB[o] = bb0; paB[o + 1] = bb1;
  paP[o] = pp0; paP[o + 1] = pp1;
}

__global__ void wkv_comb(const float* __restrict__ time_decay,
                         const float* __restrict__ paA,
                         const float* __restrict__ paB,
                         const float* __restrict__ paP,
                         float* __restrict__ inA, float* __restrict__ inB,
                         float* __restrict__ inP,
                         float* __restrict__ state, int S, int t0) {
  int idx = blockIdx.x * blockDim.x + threadIdx.x;  // [0, BB*CC)
  int c = idx & (CC - 1);
  float w = -__expf(time_decay[c]);
  float wTs = w * (float)TS;
  float A, Bv, P;
  if (t0 == 0) { A = 0.f; Bv = 0.f; P = -1e38f; }
  else { A = state[idx]; Bv = state[32768 + idx]; P = state[65536 + idx]; }
  for (int s = 0; s < S; ++s) {
    size_t o = (size_t)s * 32768 + idx;
    inA[o] = A; inB[o] = Bv; inP[o] = P;
    float Pd = P + wTs;
    float Ps = paP[o];
    float Pn = fmaxf(Pd, Ps);
    float e1 = __expf(Pd - Pn), e2 = __expf(Ps - Pn);
    A = e1 * A + e2 * paA[o];
    Bv = e1 * Bv + e2 * paB[o];
    P = Pn;
  }
  state[idx] = A; state[32768 + idx] = Bv; state[65536 + idx] = P;
}

__global__ void wkv_out(const float* __restrict__ time_decay,
                        const float* __restrict__ time_first,
                        const unsigned short* __restrict__ k,
                        const unsigned short* __restrict__ v,
                        const unsigned short* __restrict__ r,
                        unsigned short* __restrict__ rwkv,
                        const float* __restrict__ inA,
                        const float* __restrict__ inB,
                        const float* __restrict__ inP, int Tc) {
  int idx = blockIdx.x * blockDim.x + threadIdx.x;
  int c = (idx & 1023) << 1;
  int b = (idx >> 10) & (BB - 1);
  int s = idx >> 14;
  float w0 = -__expf(time_decay[c]);
  float w1 = -__expf(time_decay[c + 1]);
  float u0 = time_first[c], u1 = time_first[c + 1];
  size_t si = (size_t)s * 32768 + b * 2048 + c;
  float aa0 = inA[si], bb0 = inB[si], pp0 = inP[si];
  float aa1 = inA[si + 1], bb1 = inB[si + 1], pp1 = inP[si + 1];
  size_t base = ((size_t)b * Tc + s * TS) * CC + c;
  for (int t = 0; t < TS; ++t) {
    size_t off = base + (size_t)t * CC;
    unsigned ku = *(const unsigned*)(k + off);
    unsigned vu = *(const unsigned*)(v + off);
    unsigned ru = *(const unsigned*)(r + off);
    float kt0 = bf2f_lo(ku), kt1 = bf2f_hi(ku);
    float vt0 = bf2f_lo(vu), vt1 = bf2f_hi(vu);
    float rr0 = bf2f_lo(ru), rr1 = bf2f_hi(ru);
    float ww = u0 + kt0;
    float p = fmaxf(pp0, ww);
    float e1 = __expf(pp0 - p), e2 = __expf(ww - p);
    float y0 = (e1 * aa0 + e2 * vt0) / (e1 * bb0 + e2);
    float sr0 = 1.f / (1.f + __expf(-rr0));
    float ww2 = pp0 + w0;
    float p2 = fmaxf(ww2, kt0);
    float e1b = __expf(ww2 - p2), e2b = __expf(kt0 - p2);
    aa0 = e1b * aa0 + e2b * vt0; bb0 = e1b * bb0 + e2b; pp0 = p2;
    ww = u1 + kt1;
    p = fmaxf(pp1, ww);
    e1 = __expf(pp1 - p); e2 = __expf(ww - p);
    float y1 = (e1 * aa1 + e2 * vt1) / (e1 * bb1 + e2);
    float sr1 = 1.f / (1.f + __expf(-rr1));
    ww2 = pp1 + w1;
    p2 = fmaxf(ww2, kt1);
    e1b = __expf(ww2 - p2); e2b = __expf(kt1 - p2);
    aa1 = e1b * aa1 + e2b * vt1; bb1 = e1b * bb1 + e2b; pp1 = p2;
    unsigned out = (unsigned)f2bf(sr0 * y0) | ((unsigned)f2bf(sr1 * y1) << 16);
    *(unsigned*)(rwkv + off) = out;
  }
}

extern "C" void kernel_launch(void* const* d_in, const int* in_sizes, int n_in,
                              void* d_out, int out_size, void* d_ws,
                              size_t ws_size, hipStream_t stream) {
  const float* x          = (const float*)d_in[0];
  const float* time_decay = (const float*)d_in[1];
  const float* time_first = (const float*)d_in[2];
  const float* tmk        = (const float*)d_in[3];
  const float* tmv        = (const float*)d_in[4];
  const float* tmr        = (const float*)d_in[5];
  const float* key_w      = (const float*)d_in[6];
  const float* value_w    = (const float*)d_in[7];
  const float* rec_w      = (const float*)d_in[8];
  const float* out_w      = (const float*)d_in[9];
  float* out = (float*)d_out;

  const size_t WW = (size_t)CC * CC;
  const size_t wtBytes = 4 * WW * 2;               // 32 MB
  const size_t stBytes = 3 * (size_t)BB * CC * 4;  // 384 KB

  int Tc = 1024;
  while (Tc > 32) {
    size_t chunkBytes = (size_t)BB * Tc * CC * 12;
    if (wtBytes + stBytes + chunkBytes + 1024 <= ws_size) break;
    Tc >>= 1;
  }
  const int Mc = BB * Tc;
  const size_t NC = (size_t)Mc * CC;
  const int S = Tc / TS;

  // layout: weights | state | kbuf,vbuf,rbuf (contig) | xk,xv,xr (contig)
  char* p = (char*)d_ws;
  unsigned short* wk  = (unsigned short*)p; p += WW * 2;   // wk,wv,wrr contig
  unsigned short* wv  = (unsigned short*)p; p += WW * 2;
  unsigned short* wrr = (unsigned short*)p; p += WW * 2;
  unsigned short* wo  = (unsigned short*)p; p += WW * 2;
  float* state        = (float*)p;          p += stBytes;
  unsigned short* kbuf= (unsigned short*)p; p += NC * 2;
  unsigned short* vbuf= (unsigned short*)p; p += NC * 2;
  unsigned short* rbuf= (unsigned short*)p; p += NC * 2;
  unsigned short* xk  = (unsigned short*)p; p += NC * 2;  // aliased: rwkv
  unsigned short* xv  = (unsigned short*)p; p += NC * 2;  // aliased: scan bufs
  unsigned short* xr  = (unsigned short*)p; p += NC * 2;
  unsigned short* rwkv = xk;

  const size_t SBt = (size_t)S * 32768;
  float* paA = (float*)xv;   // xv dead after the fused projection GEMM
  float* paB = paA + SBt;
  float* paP = paB + SBt;
  float* inA = paP + SBt;
  float* inB = inA + SBt;
  float* inP = inB + SBt;

  f2bf_all<<<2048, 256, 0, stream>>>(key_w, value_w, rec_w, out_w,
                                     wk, wv, wrr, wo, (int)(WW / 4));

  int tcShift = 0;
  while ((1 << tcShift) < Tc) ++tcShift;

  const int nwg1 = (Mc / 256) * (CC / 256);       // single-matrix grid
  const int nwg3 = 3 * nwg1;                      // fused 3-matrix grid
  int mixBlocks = (Mc / 2 * (CC / 4) + 255) / 256;
  if (mixBlocks > 4096) mixBlocks = 4096;

  for (int t0 = 0; t0 < TT; t0 += Tc) {
    mix_kernel<<<mixBlocks, 256, 0, stream>>>(x, tmk, tmv, tmr, xk, xv, xr,
                                              t0, Tc);
    // fused k/v/r projections: one dispatch, which = brow>>6
    gemm256<true, true><<<nwg3, 512, 0, stream>>>(xk, wk, kbuf, CC, CC, 10, 0,
                                                  NC, NC);
    wkv_part<<<S * 64, 256, 0, stream>>>(time_decay, kbuf, vbuf,
                                         paA, paB, paP, Tc);
    wkv_comb<<<128, 256, 0, stream>>>(time_decay, paA, paB, paP,
                                      inA, inB, inP, state, S, t0);
    wkv_out<<<S * 64, 256, 0, stream>>>(time_decay, time_first, kbuf, vbuf,
                                        rbuf, rwkv, inA, inB, inP, Tc);
    gemm256<false, false><<<nwg1, 512, 0, stream>>>(rwkv, wo, out, CC, CC,
                                                    tcShift, t0, 0, 0);
  }
}